// Round 13
// baseline (138.483 us; speedup 1.0000x reference)
//
#include <hip/hip_runtime.h>
#include <cmath>

#define BB   512
#define NSV  128
#define NTRK 512
#define KK   8
#define HH   16
#define TPB  1024          // threads 0-511: half 0 (+track MLP); 512-1023: half 1 (+SV MLP)
#define RSTR 16            // global row stride: 64B line-aligned, feats only
#define PSTR 20            // padded proj stride in LDS
#define TSTR 18            // tfS stride (8B-aligned for vf2 reads)

typedef float vf2 __attribute__((ext_vector_type(2)));

__device__ __forceinline__ float elu_f(float x) {
    return x > 0.0f ? x : expm1f(x);
}
__device__ __forceinline__ unsigned umin_u(unsigned a, unsigned b) { return a < b ? a : b; }
__device__ __forceinline__ unsigned med3u(unsigned a, unsigned b, unsigned c) {
    unsigned d;
    asm("v_med3_u32 %0, %1, %2, %3" : "=v"(d) : "v"(a), "v"(b), "v"(c));
    return d;
}

// One block = one batch. 1024 threads, 2-way SV-scan split per track:
// thread tid handles track (tid&511) scanning SV half (tid>>9) * 64 rows.
// Track MLP once (threads 0-511 -> LDS); SV MLP on threads 512-639.
// Rows (64B aligned) round-trip via global ws -> one s_load_dwordx16 each;
// hsq in a side array. Depth-4 scan pipeline covers L2 scalar latency.
__global__ __launch_bounds__(TPB, 8) void fused_all(
    const float* __restrict__ x_sv, const float* __restrict__ x_trk,
    const float* __restrict__ W1s, const float* __restrict__ b1s,
    const float* __restrict__ W2s, const float* __restrict__ b2s,
    const float* __restrict__ W1t, const float* __restrict__ b1t,
    const float* __restrict__ W2t, const float* __restrict__ b2t,
    const float* __restrict__ We,  const float* __restrict__ be,
    const float* __restrict__ Wo,  const float* __restrict__ bo,
    float* __restrict__ svw,  float* __restrict__ hsw,      // ws write aliases
    const float* __restrict__ svr, const float* __restrict__ hsr, // read aliases
    float* __restrict__ out)
{
    __shared__ float    proj[NSV][PSTR];     // 10.2 KB
    __shared__ float    tfS[NTRK][TSTR];     // 36.9 KB: tf[16], htsq
    __shared__ unsigned kbuf[NTRK][KK];      // 16.4 KB: half-1 sorted lists
    __shared__ float    ucS[HH + 1];         // u[16], c0
    __shared__ float    sred[TPB / 64];

    const int b   = blockIdx.x, tid = threadIdx.x;
    const int tl  = tid & (NTRK - 1);                             // track
    const int sh  = __builtin_amdgcn_readfirstlane(tid >> 9);     // 0/1, wave-uniform

    // ---- phase A/B in parallel across thread ranges ----
    if (tid < NTRK) {
        // track MLP, once per track -> LDS
        const float* xp = x_trk + (size_t)(b * NTRK + tid) * 8;
        float x[8];
        *(float4*)&x[0] = *(const float4*)&xp[0];
        *(float4*)&x[4] = *(const float4*)&xp[4];
        float hb[HH];
        #pragma unroll
        for (int h = 0; h < HH; ++h) {
            float a = b1t[h];
            #pragma unroll
            for (int i = 0; i < 8; ++i) a += x[i] * W1t[i * HH + h];
            hb[h] = elu_f(a);
        }
        float sq = 0.0f;
        #pragma unroll
        for (int h2 = 0; h2 < HH; ++h2) {
            float a = b2t[h2];
            #pragma unroll
            for (int h = 0; h < HH; ++h) a += hb[h] * W2t[h * HH + h2];
            tfS[tid][h2] = a;
            sq += a * a;
        }
        tfS[tid][HH] = 0.5f * sq;
    } else if (tid < NTRK + NSV) {
        // SV MLP -> global rows + hsq + LDS proj
        const int s = tid - NTRK;
        const float* xp = x_sv + (size_t)(b * NSV + s) * 2;
        float x0 = xp[0], x1 = xp[1];
        float hb[HH];
        #pragma unroll
        for (int h = 0; h < HH; ++h)
            hb[h] = elu_f(x0 * W1s[h] + x1 * W1s[HH + h] + b1s[h]);
        float o[HH], sq = 0.0f;
        #pragma unroll
        for (int h2 = 0; h2 < HH; ++h2) {
            float a = b2s[h2];
            #pragma unroll
            for (int h = 0; h < HH; ++h) a += hb[h] * W2s[h * HH + h2];
            o[h2] = a;
            sq += a * a;
        }
        float* dst = svw + (size_t)(b * NSV + s) * RSTR;
        #pragma unroll
        for (int h4 = 0; h4 < 4; ++h4)
            *(float4*)&dst[h4 * 4] = make_float4(o[h4*4], o[h4*4+1], o[h4*4+2], o[h4*4+3]);
        hsw[b * NSV + s] = 0.5f * sq;
        #pragma unroll
        for (int h = 0; h < HH; ++h) {
            float a = 0.0f;
            #pragma unroll
            for (int j = 0; j < HH; ++j) a += o[j] * We[(HH + j) * HH + h];
            proj[s][h] = a;
        }
    } else if (tid < NTRK + NSV + HH) {
        int j = tid - NTRK - NSV;
        float a = 0.0f;
        #pragma unroll
        for (int h = 0; h < HH; ++h)
            a += (We[j * HH + h] - We[(HH + j) * HH + h]) * Wo[h];
        ucS[j] = a;
    } else if (tid == NTRK + NSV + HH) {
        float a = bo[0];
        #pragma unroll
        for (int h = 0; h < HH; ++h) a += be[h] * Wo[h];
        ucS[HH] = a;
    }

    __syncthreads();   // rows drained to L2; proj/uc/tf staged

    // ---- read my track's tf/htsq from LDS (one-time) ----
    vf2 ntfp[8];
    float htsq;
    #pragma unroll
    for (int j = 0; j < 8; ++j) {
        vf2 t = *(const vf2*)&tfS[tl][2 * j];
        ntfp[j] = -t;
    }
    htsq = tfS[tl][HH];

    unsigned k[KK];
    #pragma unroll
    for (int q = 0; q < KK; ++q) k[q] = 0xFFFFFFFFu;

    // ---- kNN scan of this half's 64 rows: 1x s_load_dwordx16/row, depth-4 ----
    const int sbase = sh * 64;
    const float* rp = svr + (size_t)(b * NSV + sbase) * RSTR;
    const float* hp = hsr + (size_t)b * NSV + sbase;
    const unsigned KMASK = 0xFFFFFF80u;

    vf2 p0[8], p1[8], p2[8], p3[8];
    float h0, h1, h2, h3;

    #define LOADROW(buf, hv, idx)                                      \
        do {                                                           \
            const float* _r = rp + (size_t)(idx) * RSTR;               \
            _Pragma("unroll")                                          \
            for (int _j = 0; _j < 8; ++_j)                             \
                buf[_j] = *(const vf2*)(_r + 2 * _j);                  \
            hv = hp[idx];                                              \
        } while (0)

    #define BODY(buf, hv, idx)                                         \
        do {                                                           \
            vf2 a0 = ntfp[0] * buf[0];                                 \
            vf2 a1 = ntfp[1] * buf[1];                                 \
            vf2 a2 = ntfp[2] * buf[2];                                 \
            vf2 a3 = ntfp[3] * buf[3];                                 \
            a0 = __builtin_elementwise_fma(ntfp[4], buf[4], a0);       \
            a1 = __builtin_elementwise_fma(ntfp[5], buf[5], a1);       \
            a2 = __builtin_elementwise_fma(ntfp[6], buf[6], a2);       \
            a3 = __builtin_elementwise_fma(ntfp[7], buf[7], a3);       \
            a0 = a0 + a1; a2 = a2 + a3; a0 = a0 + a2;                  \
            float e = fmaxf((htsq + hv) + (a0.x + a0.y), 0.0f);        \
            unsigned v = (__float_as_uint(e) & KMASK)                  \
                         | (unsigned)(sbase + (idx));                  \
            unsigned nk0 = umin_u(v, k[0]);                            \
            unsigned nk1 = med3u(v, k[0], k[1]);                       \
            unsigned nk2 = med3u(v, k[1], k[2]);                       \
            unsigned nk3 = med3u(v, k[2], k[3]);                       \
            unsigned nk4 = med3u(v, k[3], k[4]);                       \
            unsigned nk5 = med3u(v, k[4], k[5]);                       \
            unsigned nk6 = med3u(v, k[5], k[6]);                       \
            unsigned nk7 = med3u(v, k[6], k[7]);                       \
            k[0] = nk0; k[1] = nk1; k[2] = nk2; k[3] = nk3;            \
            k[4] = nk4; k[5] = nk5; k[6] = nk6; k[7] = nk7;            \
        } while (0)

    LOADROW(p0, h0, 0);
    LOADROW(p1, h1, 1);
    LOADROW(p2, h2, 2);
    LOADROW(p3, h3, 3);
    for (int s = 0; s < 60; s += 4) {
        BODY(p0, h0, s);     LOADROW(p0, h0, s + 4);
        BODY(p1, h1, s + 1); LOADROW(p1, h1, s + 5);
        BODY(p2, h2, s + 2); LOADROW(p2, h2, s + 6);
        BODY(p3, h3, s + 3); LOADROW(p3, h3, s + 7);
    }
    BODY(p0, h0, 60);
    BODY(p1, h1, 61);
    BODY(p2, h2, 62);
    BODY(p3, h3, 63);

    #undef LOADROW
    #undef BODY

    // ---- half 1 publishes its sorted list; half 0 merges + epilogue ----
    if (sh == 1) {
        #pragma unroll
        for (int q = 0; q < KK; ++q) kbuf[tl][q] = k[q];
    }
    __syncthreads();

    float local = 0.0f;
    if (sh == 0) {
        unsigned m[KK];    // exact 8-smallest of union (bitonic set, unsorted)
        #pragma unroll
        for (int i = 0; i < KK; ++i) m[i] = umin_u(k[i], kbuf[tl][7 - i]);

        float acc = ucS[HH];
        #pragma unroll
        for (int j = 0; j < 8; ++j) {
            acc = fmaf(-ntfp[j].x, ucS[2 * j],     acc);
            acc = fmaf(-ntfp[j].y, ucS[2 * j + 1], acc);
        }
        float mx[HH];
        #pragma unroll
        for (int h = 0; h < HH; ++h) mx[h] = -INFINITY;
        #pragma unroll
        for (int q = 0; q < KK; ++q) {
            const float* pr = &proj[m[q] & 127u][0];
            #pragma unroll
            for (int h4 = 0; h4 < 4; ++h4) {
                float4 p = *(const float4*)&pr[h4 * 4];
                mx[h4 * 4 + 0] = fmaxf(mx[h4 * 4 + 0], p.x);
                mx[h4 * 4 + 1] = fmaxf(mx[h4 * 4 + 1], p.y);
                mx[h4 * 4 + 2] = fmaxf(mx[h4 * 4 + 2], p.z);
                mx[h4 * 4 + 3] = fmaxf(mx[h4 * 4 + 3], p.w);
            }
        }
        #pragma unroll
        for (int h = 0; h < HH; ++h) acc = fmaf(mx[h], Wo[h], acc);
        local = 1.0f / (1.0f + expf(-acc));
    }

    // ---- block mean-pool (half 1 contributes zeros) ----
    #pragma unroll
    for (int off = 32; off > 0; off >>= 1)
        local += __shfl_down(local, off, 64);
    if ((tid & 63) == 0) sred[tid >> 6] = local;
    __syncthreads();
    if (tid == 0) {
        float tot = 0.0f;
        #pragma unroll
        for (int w = 0; w < TPB / 64; ++w) tot += sred[w];
        out[b]      = tot * (1.0f / NTRK);
        out[BB + b] = (float)b;
    }
}

extern "C" void kernel_launch(void* const* d_in, const int* in_sizes, int n_in,
                              void* d_out, int out_size, void* d_ws, size_t ws_size,
                              hipStream_t stream) {
    const float* x_sv  = (const float*)d_in[0];
    const float* x_trk = (const float*)d_in[1];
    const float* W1s = (const float*)d_in[4];
    const float* b1s = (const float*)d_in[5];
    const float* W2s = (const float*)d_in[6];
    const float* b2s = (const float*)d_in[7];
    const float* W1t = (const float*)d_in[8];
    const float* b1t = (const float*)d_in[9];
    const float* W2t = (const float*)d_in[10];
    const float* b2t = (const float*)d_in[11];
    const float* We  = (const float*)d_in[12];
    const float* be  = (const float*)d_in[13];
    const float* Wo  = (const float*)d_in[14];
    const float* bo  = (const float*)d_in[15];
    float* out = (float*)d_out;

    float* rows = (float*)d_ws;                        // 512*128*16 f = 4 MB, 64B rows
    float* hsq  = rows + (size_t)BB * NSV * RSTR;      // 512*128 f = 256 KB

    fused_all<<<BB, TPB, 0, stream>>>(x_sv, x_trk,
                                      W1s, b1s, W2s, b2s,
                                      W1t, b1t, W2t, b2t,
                                      We, be, Wo, bo,
                                      rows, hsq, rows, hsq, out);
}

// Round 14
// 123.431 us; speedup vs baseline: 1.1219x; 1.1219x over previous
//
#include <hip/hip_runtime.h>
#include <cmath>

#define BB   512
#define NSV  128
#define NTRK 512
#define KK   8
#define HH   16
#define TPB  1024          // threads 0-511: half 0 (+track MLP); 512-1023: half 1 (+SV MLP)
#define RSTR 20            // global row stride: [16 feats][0.5*||sv||^2][pad]
#define PSTR 20            // padded proj stride in LDS
#define TSTR 18            // tfS stride (8B-aligned for vf2 reads)

typedef float vf2 __attribute__((ext_vector_type(2)));

__device__ __forceinline__ float elu_f(float x) {
    return x > 0.0f ? x : expm1f(x);
}
__device__ __forceinline__ unsigned umin_u(unsigned a, unsigned b) { return a < b ? a : b; }
__device__ __forceinline__ unsigned med3u(unsigned a, unsigned b, unsigned c) {
    unsigned d;
    asm("v_med3_u32 %0, %1, %2, %3" : "=v"(d) : "v"(a), "v"(b), "v"(c));
    return d;
}

// One block = one batch. 1024 threads, 2-way SV-scan split per track:
// thread tid handles track (tid&511) scanning SV half (tid>>9) * 64 rows.
// Track MLP computed ONCE (threads 0-511 -> LDS). SV MLP on threads 512-639.
// Rows round-trip via global ws (scalar-load path, L2-hot). Half 1 publishes
// its sorted top-8; half 0 merges exactly and runs the epilogue alone.
// [R13 errata: 64B rows + split hsq + depth-4 de-pipelined (shared ooo
//  lgkmcnt) and regressed 42.9->58; this R12 form is the measured optimum.]
__global__ __launch_bounds__(TPB, 8) void fused_all(
    const float* __restrict__ x_sv, const float* __restrict__ x_trk,
    const float* __restrict__ W1s, const float* __restrict__ b1s,
    const float* __restrict__ W2s, const float* __restrict__ b2s,
    const float* __restrict__ W1t, const float* __restrict__ b1t,
    const float* __restrict__ W2t, const float* __restrict__ b2t,
    const float* __restrict__ We,  const float* __restrict__ be,
    const float* __restrict__ Wo,  const float* __restrict__ bo,
    float* __restrict__ svw,             // ws rows, write alias
    const float* __restrict__ svr,       // ws rows, read alias (scalar loads)
    float* __restrict__ out)
{
    __shared__ float    proj[NSV][PSTR];     // 10.2 KB
    __shared__ float    tfS[NTRK][TSTR];     // 36.9 KB: tf[16], htsq
    __shared__ unsigned kbuf[NTRK][KK];      // 16.4 KB: half-1 sorted lists
    __shared__ float    ucS[HH + 1];         // u[16], c0
    __shared__ float    sred[TPB / 64];

    const int b   = blockIdx.x, tid = threadIdx.x;
    const int tl  = tid & (NTRK - 1);                             // track
    const int sh  = __builtin_amdgcn_readfirstlane(tid >> 9);     // 0/1, wave-uniform

    // ---- phase A/B in parallel across thread ranges ----
    if (tid < NTRK) {
        // track MLP, once per track -> LDS
        const float* xp = x_trk + (size_t)(b * NTRK + tid) * 8;
        float x[8];
        *(float4*)&x[0] = *(const float4*)&xp[0];
        *(float4*)&x[4] = *(const float4*)&xp[4];
        float hb[HH];
        #pragma unroll
        for (int h = 0; h < HH; ++h) {
            float a = b1t[h];
            #pragma unroll
            for (int i = 0; i < 8; ++i) a += x[i] * W1t[i * HH + h];
            hb[h] = elu_f(a);
        }
        float sq = 0.0f;
        #pragma unroll
        for (int h2 = 0; h2 < HH; ++h2) {
            float a = b2t[h2];
            #pragma unroll
            for (int h = 0; h < HH; ++h) a += hb[h] * W2t[h * HH + h2];
            tfS[tid][h2] = a;
            sq += a * a;
        }
        tfS[tid][HH] = 0.5f * sq;
    } else if (tid < NTRK + NSV) {
        // SV MLP -> global rows + LDS proj
        const int s = tid - NTRK;
        const float* xp = x_sv + (size_t)(b * NSV + s) * 2;
        float x0 = xp[0], x1 = xp[1];
        float hb[HH];
        #pragma unroll
        for (int h = 0; h < HH; ++h)
            hb[h] = elu_f(x0 * W1s[h] + x1 * W1s[HH + h] + b1s[h]);
        float o[HH], sq = 0.0f;
        #pragma unroll
        for (int h2 = 0; h2 < HH; ++h2) {
            float a = b2s[h2];
            #pragma unroll
            for (int h = 0; h < HH; ++h) a += hb[h] * W2s[h * HH + h2];
            o[h2] = a;
            sq += a * a;
        }
        float* dst = svw + (size_t)(b * NSV + s) * RSTR;
        #pragma unroll
        for (int h4 = 0; h4 < 4; ++h4)
            *(float4*)&dst[h4 * 4] = make_float4(o[h4*4], o[h4*4+1], o[h4*4+2], o[h4*4+3]);
        dst[HH] = 0.5f * sq;
        #pragma unroll
        for (int h = 0; h < HH; ++h) {
            float a = 0.0f;
            #pragma unroll
            for (int j = 0; j < HH; ++j) a += o[j] * We[(HH + j) * HH + h];
            proj[s][h] = a;
        }
    } else if (tid < NTRK + NSV + HH) {
        int j = tid - NTRK - NSV;
        float a = 0.0f;
        #pragma unroll
        for (int h = 0; h < HH; ++h)
            a += (We[j * HH + h] - We[(HH + j) * HH + h]) * Wo[h];
        ucS[j] = a;
    } else if (tid == NTRK + NSV + HH) {
        float a = bo[0];
        #pragma unroll
        for (int h = 0; h < HH; ++h) a += be[h] * Wo[h];
        ucS[HH] = a;
    }

    __syncthreads();   // rows drained to L2; proj/uc/tf staged

    // ---- read my track's tf/htsq from LDS (one-time) ----
    vf2 ntfp[8];
    float htsq;
    #pragma unroll
    for (int j = 0; j < 8; ++j) {
        vf2 t = *(const vf2*)&tfS[tl][2 * j];
        ntfp[j] = -t;
    }
    htsq = tfS[tl][HH];

    unsigned k[KK];
    #pragma unroll
    for (int q = 0; q < KK; ++q) k[q] = 0xFFFFFFFFu;

    // ---- kNN scan of this half's 64 rows: scalar loads, depth-3 pipeline ----
    const int sbase = sh * 64;
    const float* rp = svr + (size_t)(b * NSV + sbase) * RSTR;

    vf2 p0[8], p1[8], p2[8]; float h0, h1, h2;

    #define LOADROW(buf, hv, idx)                                      \
        do {                                                           \
            const float* _r = rp + (size_t)(idx) * RSTR;               \
            _Pragma("unroll")                                          \
            for (int _j = 0; _j < 8; ++_j)                             \
                buf[_j] = *(const vf2*)(_r + 2 * _j);                  \
            hv = _r[HH];                                               \
        } while (0)

    #define BODY(buf, hv, idx)                                         \
        do {                                                           \
            vf2 a0 = ntfp[0] * buf[0];                                 \
            vf2 a1 = ntfp[1] * buf[1];                                 \
            vf2 a2 = ntfp[2] * buf[2];                                 \
            vf2 a3 = ntfp[3] * buf[3];                                 \
            a0 = __builtin_elementwise_fma(ntfp[4], buf[4], a0);       \
            a1 = __builtin_elementwise_fma(ntfp[5], buf[5], a1);       \
            a2 = __builtin_elementwise_fma(ntfp[6], buf[6], a2);       \
            a3 = __builtin_elementwise_fma(ntfp[7], buf[7], a3);       \
            a0 = a0 + a1; a2 = a2 + a3; a0 = a0 + a2;                  \
            float e = fmaxf((htsq + hv) + (a0.x + a0.y), 0.0f);        \
            unsigned v = (__float_as_uint(e) & 0xFFFFFF80u)            \
                         | (unsigned)(sbase + (idx));                  \
            unsigned nk0 = umin_u(v, k[0]);                            \
            unsigned nk1 = med3u(v, k[0], k[1]);                       \
            unsigned nk2 = med3u(v, k[1], k[2]);                       \
            unsigned nk3 = med3u(v, k[2], k[3]);                       \
            unsigned nk4 = med3u(v, k[3], k[4]);                       \
            unsigned nk5 = med3u(v, k[4], k[5]);                       \
            unsigned nk6 = med3u(v, k[5], k[6]);                       \
            unsigned nk7 = med3u(v, k[6], k[7]);                       \
            k[0] = nk0; k[1] = nk1; k[2] = nk2; k[3] = nk3;            \
            k[4] = nk4; k[5] = nk5; k[6] = nk6; k[7] = nk7;            \
        } while (0)

    LOADROW(p0, h0, 0);
    LOADROW(p1, h1, 1);
    LOADROW(p2, h2, 2);
    for (int s = 0; s < 60; s += 3) {
        BODY(p0, h0, s);     LOADROW(p0, h0, s + 3);
        BODY(p1, h1, s + 1); LOADROW(p1, h1, s + 4);
        BODY(p2, h2, s + 2); LOADROW(p2, h2, s + 5);
    }
    BODY(p0, h0, 60); LOADROW(p0, h0, 63);
    BODY(p1, h1, 61);
    BODY(p2, h2, 62);
    BODY(p0, h0, 63);

    #undef LOADROW
    #undef BODY

    // ---- half 1 publishes its sorted list; half 0 merges + epilogue ----
    if (sh == 1) {
        #pragma unroll
        for (int q = 0; q < KK; ++q) kbuf[tl][q] = k[q];
    }
    __syncthreads();

    float local = 0.0f;
    if (sh == 0) {
        unsigned m[KK];    // exact 8-smallest of union (bitonic set, unsorted)
        #pragma unroll
        for (int i = 0; i < KK; ++i) m[i] = umin_u(k[i], kbuf[tl][7 - i]);

        float acc = ucS[HH];
        #pragma unroll
        for (int j = 0; j < 8; ++j) {
            acc = fmaf(-ntfp[j].x, ucS[2 * j],     acc);
            acc = fmaf(-ntfp[j].y, ucS[2 * j + 1], acc);
        }
        float mx[HH];
        #pragma unroll
        for (int h = 0; h < HH; ++h) mx[h] = -INFINITY;
        #pragma unroll
        for (int q = 0; q < KK; ++q) {
            const float* pr = &proj[m[q] & 127u][0];
            #pragma unroll
            for (int h4 = 0; h4 < 4; ++h4) {
                float4 p = *(const float4*)&pr[h4 * 4];
                mx[h4 * 4 + 0] = fmaxf(mx[h4 * 4 + 0], p.x);
                mx[h4 * 4 + 1] = fmaxf(mx[h4 * 4 + 1], p.y);
                mx[h4 * 4 + 2] = fmaxf(mx[h4 * 4 + 2], p.z);
                mx[h4 * 4 + 3] = fmaxf(mx[h4 * 4 + 3], p.w);
            }
        }
        #pragma unroll
        for (int h = 0; h < HH; ++h) acc = fmaf(mx[h], Wo[h], acc);
        local = 1.0f / (1.0f + expf(-acc));
    }

    // ---- block mean-pool (half 1 contributes zeros) ----
    #pragma unroll
    for (int off = 32; off > 0; off >>= 1)
        local += __shfl_down(local, off, 64);
    if ((tid & 63) == 0) sred[tid >> 6] = local;
    __syncthreads();
    if (tid == 0) {
        float tot = 0.0f;
        #pragma unroll
        for (int w = 0; w < TPB / 64; ++w) tot += sred[w];
        out[b]      = tot * (1.0f / NTRK);
        out[BB + b] = (float)b;
    }
}

extern "C" void kernel_launch(void* const* d_in, const int* in_sizes, int n_in,
                              void* d_out, int out_size, void* d_ws, size_t ws_size,
                              hipStream_t stream) {
    const float* x_sv  = (const float*)d_in[0];
    const float* x_trk = (const float*)d_in[1];
    const float* W1s = (const float*)d_in[4];
    const float* b1s = (const float*)d_in[5];
    const float* W2s = (const float*)d_in[6];
    const float* b2s = (const float*)d_in[7];
    const float* W1t = (const float*)d_in[8];
    const float* b1t = (const float*)d_in[9];
    const float* W2t = (const float*)d_in[10];
    const float* b2t = (const float*)d_in[11];
    const float* We  = (const float*)d_in[12];
    const float* be  = (const float*)d_in[13];
    const float* Wo  = (const float*)d_in[14];
    const float* bo  = (const float*)d_in[15];
    float* out = (float*)d_out;

    float* rows = (float*)d_ws;      // 512*128*20 floats = 5.24 MB

    fused_all<<<BB, TPB, 0, stream>>>(x_sv, x_trk,
                                      W1s, b1s, W2s, b2s,
                                      W1t, b1t, W2t, b2t,
                                      We, be, Wo, bo,
                                      rows, rows, out);
}